// Round 10
// baseline (1843.134 us; speedup 1.0000x reference)
//
#include <hip/hip_runtime.h>
#include <math.h>

#define N_    2048
#define D0_   256
#define D1_   128
#define D2_   32
#define F_    416
#define H_    4
#define DH_   64
#define L_    4
#define NC_   10
#define C2_   1.7320508075688772f
#define X12W  544

typedef unsigned short u16;
typedef __attribute__((ext_vector_type(8))) short short8v;
typedef __attribute__((ext_vector_type(4))) float f32x4;

union U8 { u16 u[8]; short8v v; };

__device__ __forceinline__ u16 f2bf(float f) {
    union { float f; unsigned int u; } x; x.f = f;
    unsigned int r = x.u + 0x7FFFu + ((x.u >> 16) & 1u);
    return (u16)(r >> 16);
}
__device__ __forceinline__ float bf2f(u16 u) {
    union { float f; unsigned int u; } x; x.u = ((unsigned int)u) << 16;
    return x.f;
}
__device__ __forceinline__ f32x4 mfma16(short8v a, short8v b, f32x4 c) {
    return __builtin_amdgcn_mfma_f32_16x16x32_bf16(a, b, c, 0, 0, 0);
}

// ================= MFMA GEMM (dense layers) =================
enum { B_NN = 0, B_NT = 1 };
enum { EPI_STORE = 0, EPI_SILU = 1, EPI_SIGMOID = 2, EPI_ACCUM = 3, EPI_ATOMIC = 4 };

template<int BLAY, int EPI>
__global__ __launch_bounds__(256) void mfma_gemm(
    const float* __restrict__ A, int lda,
    const float* __restrict__ B, int ldb,
    const float* __restrict__ bias,
    float* __restrict__ C, int ldc,
    int M, int K, int Nn, float scale, int kchunk)
{
    __shared__ __align__(16) u16 As[64][40];
    __shared__ __align__(16) u16 Bs[64][40];
    const int t = threadIdx.x;
    const int bm = blockIdx.y * 64, bn = blockIdx.x * 64;
    const int lane = t & 63, w = t >> 6;
    const int r0 = (w >> 1) * 32, c0 = (w & 1) * 32;
    const int fr = lane & 15, fk = (lane >> 4) * 8;
    const int ml = t >> 2, k8 = (t & 3) * 8;
    const int kbeg = blockIdx.z * kchunk;
    const int kend = (kbeg + kchunk < K) ? kbeg + kchunk : K;
    f32x4 acc[2][2] = {};

    for (int k0 = kbeg; k0 < kend; k0 += 32) {
        {
            U8 u;
            if (((lda & 3) == 0) && (k0 + 32 <= kend)) {
                const float* ap = A + (size_t)(bm + ml) * lda + k0 + k8;
                float4 a0 = *(const float4*)ap;
                float4 a1 = *(const float4*)(ap + 4);
                u.u[0]=f2bf(a0.x); u.u[1]=f2bf(a0.y); u.u[2]=f2bf(a0.z); u.u[3]=f2bf(a0.w);
                u.u[4]=f2bf(a1.x); u.u[5]=f2bf(a1.y); u.u[6]=f2bf(a1.z); u.u[7]=f2bf(a1.w);
            } else {
#pragma unroll
                for (int j = 0; j < 8; ++j) {
                    int kk = k0 + k8 + j;
                    u.u[j] = f2bf(kk < kend ? A[(size_t)(bm + ml) * lda + kk] : 0.f);
                }
            }
            *(short8v*)&As[ml][k8] = u.v;
        }
        {
            U8 u;
            if (BLAY == B_NT) {
#pragma unroll
                for (int j = 0; j < 8; ++j) {
                    int kk = k0 + k8 + j;
                    u.u[j] = f2bf((kk < kend && bn + ml < Nn)
                                  ? B[(size_t)(bn + ml) * ldb + kk] : 0.f);
                }
            } else {
                int nc = bn + ml;
#pragma unroll
                for (int j = 0; j < 8; ++j) {
                    int kk = k0 + k8 + j;
                    u.u[j] = f2bf((kk < kend && nc < Nn) ? B[(size_t)kk * ldb + nc] : 0.f);
                }
            }
            *(short8v*)&Bs[ml][k8] = u.v;
        }
        __syncthreads();
        short8v a0 = *(const short8v*)&As[r0 + fr][fk];
        short8v a1 = *(const short8v*)&As[r0 + 16 + fr][fk];
        short8v b0 = *(const short8v*)&Bs[c0 + fr][fk];
        short8v b1 = *(const short8v*)&Bs[c0 + 16 + fr][fk];
        acc[0][0] = mfma16(a0, b0, acc[0][0]);
        acc[0][1] = mfma16(a0, b1, acc[0][1]);
        acc[1][0] = mfma16(a1, b0, acc[1][0]);
        acc[1][1] = mfma16(a1, b1, acc[1][1]);
        __syncthreads();
    }
#pragma unroll
    for (int mi = 0; mi < 2; ++mi)
#pragma unroll
    for (int ni = 0; ni < 2; ++ni)
#pragma unroll
    for (int r = 0; r < 4; ++r) {
        int row = bm + r0 + mi * 16 + ((lane >> 4) << 2) + r;
        int col = bn + c0 + ni * 16 + fr;
        if (col >= Nn) continue;
        float v = acc[mi][ni][r];
        float* cp = C + (size_t)row * ldc + col;
        if (EPI == EPI_STORE)   *cp = v * scale + (bias ? bias[col] : 0.f);
        if (EPI == EPI_SILU)    *cp = v / (1.f + expf(-v));
        if (EPI == EPI_SIGMOID) *cp = 1.f / (1.f + expf(-v));
        if (EPI == EPI_ACCUM)   *cp += v;
        if (EPI == EPI_ATOMIC)  atomicAdd(cp, v);
    }
}

// --------- transpose: in [R][C] f32 -> out [C][R] bf16 ---------
__global__ __launch_bounds__(256) void transpose_bf16(
    const float* __restrict__ in, u16* __restrict__ outT, int R, int C)
{
    __shared__ float tile[64][65];
    const int br = blockIdx.y * 64, bc = blockIdx.x * 64;
    const int t = threadIdx.x, lc = t & 63, q = t >> 6;
#pragma unroll 4
    for (int r = 0; r < 16; ++r) {
        int row = br + q * 16 + r, col = bc + lc;
        tile[q * 16 + r][lc] = (col < C) ? in[(size_t)row * C + col] : 0.f;
    }
    __syncthreads();
#pragma unroll 4
    for (int r = 0; r < 16; ++r) {
        int orow = bc + q * 16 + r;
        int ocol = br + lc;
        if (orow < C) outT[(size_t)orow * R + ocol] = f2bf(tile[lc][q * 16 + r]);
    }
}

// ============ aggP: bf16 A [M][K] @ bf16 BT [Nn][K] -> atomic C ============
template<int NB>
__global__ __launch_bounds__(256) void aggP(
    const u16* __restrict__ A, int lda,
    const u16* __restrict__ BT, int ldk,
    float* __restrict__ C, int ldc,
    int K, int Nn, int kchunk, int zk)
{
    __shared__ __align__(16) u16 As[64][40];
    __shared__ __align__(16) u16 Bs[NB][64][40];
    const int t = threadIdx.x;
    const int bm = blockIdx.y * 64, bn0 = blockIdx.x * 64 * NB;
    const int kz = blockIdx.z % zk;
    const int lane = t & 63, w = t >> 6;
    const int r0 = (w >> 1) * 32, c0 = (w & 1) * 32;
    const int fr = lane & 15, fk = (lane >> 4) * 8;
    const int ml = t >> 2, k8 = (t & 3) * 8;
    const int kbeg = kz * kchunk;
    const int kend = (kbeg + kchunk < K) ? kbeg + kchunk : K;
    f32x4 acc[NB][2][2] = {};

    for (int k0 = kbeg; k0 < kend; k0 += 32) {
        *(short8v*)&As[ml][k8] = *(const short8v*)(A + (size_t)(bm + ml) * lda + k0 + k8);
#pragma unroll
        for (int nb = 0; nb < NB; ++nb) {
            int nc = bn0 + nb * 64 + ml;
            short8v z = {};
            *(short8v*)&Bs[nb][ml][k8] = (nc < Nn)
                ? *(const short8v*)(BT + (size_t)nc * ldk + k0 + k8) : z;
        }
        __syncthreads();
        short8v a0 = *(const short8v*)&As[r0 + fr][fk];
        short8v a1 = *(const short8v*)&As[r0 + 16 + fr][fk];
#pragma unroll
        for (int nb = 0; nb < NB; ++nb) {
            short8v b0 = *(const short8v*)&Bs[nb][c0 + fr][fk];
            short8v b1 = *(const short8v*)&Bs[nb][c0 + 16 + fr][fk];
            acc[nb][0][0] = mfma16(a0, b0, acc[nb][0][0]);
            acc[nb][0][1] = mfma16(a0, b1, acc[nb][0][1]);
            acc[nb][1][0] = mfma16(a1, b0, acc[nb][1][0]);
            acc[nb][1][1] = mfma16(a1, b1, acc[nb][1][1]);
        }
        __syncthreads();
    }
#pragma unroll
    for (int nb = 0; nb < NB; ++nb)
#pragma unroll
    for (int mi = 0; mi < 2; ++mi)
#pragma unroll
    for (int ni = 0; ni < 2; ++ni)
#pragma unroll
    for (int r = 0; r < 4; ++r) {
        int row = bm + r0 + mi * 16 + ((lane >> 4) << 2) + r;
        int col = bn0 + nb * 64 + c0 + ni * 16 + fr;
        if (col >= Nn) continue;
        atomicAdd(C + (size_t)row * ldc + col, acc[nb][mi][ni][r]);
    }
}

// ---------------- u precompute ----------------
__global__ void ucompute_kernel(const float* __restrict__ pos, u16* __restrict__ U) {
    int idx = blockIdx.x * 256 + threadIdx.x;
    int n = idx >> 11, m = idx & (N_ - 1);
    float rx = pos[m * 3 + 0] - pos[n * 3 + 0];
    float ry = pos[m * 3 + 1] - pos[n * 3 + 1];
    float rz = pos[m * 3 + 2] - pos[n * 3 + 2];
    float d2 = rx * rx + ry * ry + rz * rz;
    bool valid = d2 > 1e-12f;
    float rinv = valid ? rsqrtf(d2) : 0.f;
    size_t base = (size_t)n * N_ + m;
    const size_t CS = (size_t)N_ * N_;
    U[base]          = f2bf(rx * rinv);
    U[base + CS]     = f2bf(ry * rinv);
    U[base + 2 * CS] = f2bf(rz * rinv);
}

// ============ fused mix: all channels of one degree per block ============
// DEG=1: 3 channels, B=s1T (2 col-tiles).  DEG=2: 5 channels, B=s2T (32 cols).
// grid (8, 32): x = ks (kchunk 256), y = row-block.
template<int DEG>
__global__ __launch_bounds__(256) void mixf_kernel(
    const u16* __restrict__ amb, const u16* __restrict__ U,
    const u16* __restrict__ BT, float* __restrict__ Macc)
{
    constexpr int NCH = (DEG == 1) ? 3 : 5;
    constexpr int NCT = (DEG == 1) ? 2 : 1;
    const int bm = blockIdx.y * 64;
    const size_t CS = (size_t)N_ * N_;
    __shared__ __align__(16) u16 As[NCH][64][40];
    __shared__ __align__(16) u16 Bs[NCT][64][40];
    const int t = threadIdx.x, lane = t & 63, w = t >> 6;
    const int r0 = (w >> 1) * 32, c0 = (w & 1) * 32;
    const int fr = lane & 15, fk = (lane >> 4) * 8;
    const int ml = t >> 2, k8 = (t & 3) * 8;
    const int kbeg = blockIdx.x * 256, kend = kbeg + 256;
    f32x4 acc[NCH][NCT][2][2] = {};

    for (int m0 = kbeg; m0 < kend; m0 += 32) {
        const size_t off = (size_t)(bm + ml) * N_ + m0 + k8;
        U8 am8; am8.v = *(const short8v*)(amb + off);
        U8 xv, yv, zv;
        xv.v = *(const short8v*)(U + off);
        yv.v = *(const short8v*)(U + CS + off);
        zv.v = *(const short8v*)(U + 2 * CS + off);
        if (DEG == 1) {
            U8 o0, o1, o2;
#pragma unroll
            for (int j = 0; j < 8; ++j) {
                float a = bf2f(am8.u[j]);
                o0.u[j] = f2bf(a * bf2f(xv.u[j]));
                o1.u[j] = f2bf(a * bf2f(yv.u[j]));
                o2.u[j] = f2bf(a * bf2f(zv.u[j]));
            }
            *(short8v*)&As[0][ml][k8] = o0.v;
            *(short8v*)&As[1][ml][k8] = o1.v;
            *(short8v*)&As[2][ml][k8] = o2.v;
        } else {
            U8 o[5];
#pragma unroll
            for (int j = 0; j < 8; ++j) {
                float a = bf2f(am8.u[j]);
                float ux = bf2f(xv.u[j]), uy = bf2f(yv.u[j]), uz = bf2f(zv.u[j]);
                o[0].u[j] = f2bf(a * C2_ * ux * uy);
                o[1].u[j] = f2bf(a * C2_ * uy * uz);
                o[2].u[j] = f2bf((ux*ux + uy*uy + uz*uz > 0.5f)
                                 ? a * 0.5f * (3.f * uz * uz - 1.f) : 0.f);
                o[3].u[j] = f2bf(a * C2_ * ux * uz);
                o[4].u[j] = f2bf(a * 0.5f * C2_ * (ux * ux - uy * uy));
            }
#pragma unroll
            for (int c = 0; c < 5; ++c) *(short8v*)&As[c][ml][k8] = o[c].v;
        }
#pragma unroll
        for (int ct = 0; ct < NCT; ++ct) {
            int nc = ct * 64 + ml;
            short8v z = {};
            *(short8v*)&Bs[ct][ml][k8] = (DEG == 1 || nc < 32)
                ? *(const short8v*)(BT + (size_t)nc * N_ + m0 + k8) : z;
        }
        __syncthreads();
#pragma unroll
        for (int c = 0; c < NCH; ++c) {
            short8v a0 = *(const short8v*)&As[c][r0 + fr][fk];
            short8v a1 = *(const short8v*)&As[c][r0 + 16 + fr][fk];
#pragma unroll
            for (int ct = 0; ct < NCT; ++ct) {
                short8v b0 = *(const short8v*)&Bs[ct][c0 + fr][fk];
                short8v b1 = *(const short8v*)&Bs[ct][c0 + 16 + fr][fk];
                acc[c][ct][0][0] = mfma16(a0, b0, acc[c][ct][0][0]);
                acc[c][ct][0][1] = mfma16(a0, b1, acc[c][ct][0][1]);
                acc[c][ct][1][0] = mfma16(a1, b0, acc[c][ct][1][0]);
                acc[c][ct][1][1] = mfma16(a1, b1, acc[c][ct][1][1]);
            }
        }
        __syncthreads();
    }
#pragma unroll
    for (int c = 0; c < NCH; ++c)
#pragma unroll
    for (int ct = 0; ct < NCT; ++ct)
#pragma unroll
    for (int mi = 0; mi < 2; ++mi)
#pragma unroll
    for (int ni = 0; ni < 2; ++ni)
#pragma unroll
    for (int r = 0; r < 4; ++r) {
        int row = bm + r0 + mi * 16 + ((lane >> 4) << 2) + r;
        int col = ct * 64 + c0 + ni * 16 + fr;
        float v = acc[c][ct][mi][ni][r];
        if (DEG == 1)
            atomicAdd(&Macc[(size_t)c * N_ * 128 + (size_t)row * 128 + col], v);
        else if (col < 32)
            atomicAdd(&Macc[(size_t)3 * N_ * 128 + (size_t)c * N_ * 32
                            + (size_t)row * 32 + col], v);
    }
}

// -------- combine: x12 += Macc --------
__global__ void mix_combine(const float* __restrict__ Macc, float* __restrict__ x12) {
    int idx = blockIdx.x * 256 + threadIdx.x;
    if (idx >= N_ * X12W) return;
    int n = idx / X12W, j = idx % X12W;
    float v;
    if (j < 384) {
        int e = j / 3, c = j - 3 * e;
        v = Macc[(size_t)c * N_ * 128 + (size_t)n * 128 + e];
    } else {
        int jj = j - 384;
        int e = jj / 5, c = jj - 5 * e;
        v = Macc[(size_t)3 * N_ * 128 + (size_t)c * N_ * 32 + (size_t)n * 32 + e];
    }
    x12[idx] += v;
}

// ============ attention pass 1: per-row online max/sum (per head) ============
// grid (32 rowblocks, 4 heads); 256 thr = 4 waves, wave w owns rows w*16..+16.
__global__ __launch_bounds__(256) void attn_pass1(
    const float* __restrict__ q, const float* __restrict__ k,
    float* __restrict__ rsm, float* __restrict__ rsl)
{
    const int n0 = blockIdx.x * 64, h = blockIdx.y;
    __shared__ __align__(16) u16 qs[64][72];
    __shared__ __align__(16) u16 kt[64][72];
    const int t = threadIdx.x, lane = t & 63, w = t >> 6;
    const int fr = lane & 15, fk = (lane >> 4) * 8;
    const int sr = t >> 2, sc = (t & 3) * 16;
    {
        const float* qp = q + (size_t)(n0 + sr) * 256 + h * 64 + sc;
        U8 u0, u1;
#pragma unroll
        for (int j = 0; j < 8; ++j) { u0.u[j] = f2bf(qp[j]); u1.u[j] = f2bf(qp[8 + j]); }
        *(short8v*)&qs[sr][sc] = u0.v;
        *(short8v*)&qs[sr][sc + 8] = u1.v;
    }
    float mrun[4] = {-1e30f, -1e30f, -1e30f, -1e30f};
    float lrun[4] = {};
    const int rw = w * 16;

    for (int m0 = 0; m0 < N_; m0 += 64) {
        __syncthreads();
        {
            const float* kp = k + (size_t)(m0 + sr) * 256 + h * 64 + sc;
            U8 u0, u1;
#pragma unroll
            for (int j = 0; j < 8; ++j) { u0.u[j] = f2bf(kp[j]); u1.u[j] = f2bf(kp[8 + j]); }
            *(short8v*)&kt[sr][sc] = u0.v;
            *(short8v*)&kt[sr][sc + 8] = u1.v;
        }
        __syncthreads();
        short8v a0 = *(const short8v*)&qs[rw + fr][fk];
        short8v a1 = *(const short8v*)&qs[rw + fr][32 + fk];
        f32x4 sacc[4] = {};
#pragma unroll
        for (int ni = 0; ni < 4; ++ni) {
            short8v b0 = *(const short8v*)&kt[ni * 16 + fr][fk];
            short8v b1 = *(const short8v*)&kt[ni * 16 + fr][32 + fk];
            sacc[ni] = mfma16(a1, b1, mfma16(a0, b0, sacc[ni]));
        }
#pragma unroll
        for (int r = 0; r < 4; ++r) {
            float tm = -1e30f;
#pragma unroll
            for (int ni = 0; ni < 4; ++ni) tm = fmaxf(tm, sacc[ni][r] * 0.125f);
            tm = fmaxf(tm, __shfl_xor(tm, 1));
            tm = fmaxf(tm, __shfl_xor(tm, 2));
            tm = fmaxf(tm, __shfl_xor(tm, 4));
            tm = fmaxf(tm, __shfl_xor(tm, 8));
            float mn = fmaxf(mrun[r], tm);
            float ts = 0.f;
#pragma unroll
            for (int ni = 0; ni < 4; ++ni) ts += expf(sacc[ni][r] * 0.125f - mn);
            ts += __shfl_xor(ts, 1);
            ts += __shfl_xor(ts, 2);
            ts += __shfl_xor(ts, 4);
            ts += __shfl_xor(ts, 8);
            lrun[r] = lrun[r] * expf(mrun[r] - mn) + ts;
            mrun[r] = mn;
        }
    }
    if (fr == 0) {
#pragma unroll
        for (int r = 0; r < 4; ++r) {
            int row = n0 + rw + (lane >> 4) * 4 + r;
            rsm[(size_t)h * N_ + row] = mrun[r];
            rsl[(size_t)h * N_ + row] = 1.f / lrun[r];
        }
    }
}

// ============ attention pass 2: P on the fly -> amb + x0 += P@V ============
// grid (32 rowblocks, 4 m-splits of 512); 4 waves, wave w owns rows w*16..+16.
__global__ __launch_bounds__(256) void attn_pass2(
    const float* __restrict__ q, const float* __restrict__ k,
    const u16* __restrict__ v0T,
    const float* __restrict__ rsm, const float* __restrict__ rsl,
    u16* __restrict__ amb, float* __restrict__ x0)
{
    const int n0 = blockIdx.x * 64, mbase = blockIdx.y * 512;
    __shared__ __align__(16) u16 qs[64][264];
    __shared__ __align__(16) u16 kt[64][72];
    __shared__ __align__(16) u16 vt[64][72];
    __shared__ __align__(16) u16 Plds[4][16][72];
    const int t = threadIdx.x, lane = t & 63, w = t >> 6;
    const int fr = lane & 15, fk = (lane >> 4) * 8;
    const int sr = t >> 2, sc = (t & 3) * 16;
    const int rw = w * 16;
    {
#pragma unroll
        for (int seg = 0; seg < 4; ++seg) {
            const float* qp = q + (size_t)(n0 + sr) * 256 + seg * 64 + sc;
            U8 u0, u1;
#pragma unroll
            for (int j = 0; j < 8; ++j) { u0.u[j] = f2bf(qp[j]); u1.u[j] = f2bf(qp[8 + j]); }
            *(short8v*)&qs[sr][seg * 64 + sc] = u0.v;
            *(short8v*)&qs[sr][seg * 64 + sc + 8] = u1.v;
        }
    }
    f32x4 oacc[4][4] = {};

    for (int mt = 0; mt < 8; ++mt) {
        const int m0 = mbase + mt * 64;
        f32x4 amac[4] = {};
#pragma unroll
        for (int h = 0; h < 4; ++h) {
            __syncthreads();
            {
                const float* kp = k + (size_t)(m0 + sr) * 256 + h * 64 + sc;
                U8 u0, u1;
#pragma unroll
                for (int j = 0; j < 8; ++j) { u0.u[j] = f2bf(kp[j]); u1.u[j] = f2bf(kp[8 + j]); }
                *(short8v*)&kt[sr][sc] = u0.v;
                *(short8v*)&kt[sr][sc + 8] = u1.v;
                *(short8v*)&vt[sr][sc] =
                    *(const short8v*)(v0T + (size_t)(h * 64 + sr) * N_ + m0 + sc);
                *(short8v*)&vt[sr][sc + 8] =
                    *(const short8v*)(v0T + (size_t)(h * 64 + sr) * N_ + m0 + sc + 8);
            }
            __syncthreads();
            short8v a0 = *(const short8v*)&qs[rw + fr][h * 64 + fk];
            short8v a1 = *(const short8v*)&qs[rw + fr][h * 64 + 32 + fk];
            float mf[4], lf[4];
#pragma unroll
            for (int r = 0; r < 4; ++r) {
                int row = n0 + rw + (lane >> 4) * 4 + r;
                mf[r] = rsm[(size_t)h * N_ + row];
                lf[r] = rsl[(size_t)h * N_ + row];
            }
#pragma unroll
            for (int ni = 0; ni < 4; ++ni) {
                short8v b0 = *(const short8v*)&kt[ni * 16 + fr][fk];
                short8v b1 = *(const short8v*)&kt[ni * 16 + fr][32 + fk];
                f32x4 sacc = {};
                sacc = mfma16(a1, b1, mfma16(a0, b0, sacc));
#pragma unroll
                for (int r = 0; r < 4; ++r) {
                    float pv = expf(sacc[r] * 0.125f - mf[r]) * lf[r];
                    amac[ni][r] += 0.25f * pv;
                    Plds[w][(lane >> 4) * 4 + r][ni * 16 + fr] = f2bf(pv);
                }
            }
            __syncthreads();
            short8v pa0 = *(const short8v*)&Plds[w][fr][fk];
            short8v pa1 = *(const short8v*)&Plds[w][fr][32 + fk];
#pragma unroll
            for (int ni = 0; ni < 4; ++ni) {
                short8v b0 = *(const short8v*)&vt[ni * 16 + fr][fk];
                short8v b1 = *(const short8v*)&vt[ni * 16 + fr][32 + fk];
                oacc[h][ni] = mfma16(pa1, b1, mfma16(pa0, b0, oacc[h][ni]));
            }
        }
        // write am tile (unique rows x m-cols; dense bf16 stores)
#pragma unroll
        for (int ni = 0; ni < 4; ++ni)
#pragma unroll
        for (int r = 0; r < 4; ++r) {
            int row = n0 + rw + (lane >> 4) * 4 + r;
            amb[(size_t)row * N_ + m0 + ni * 16 + fr] = f2bf(amac[ni][r]);
        }
    }
#pragma unroll
    for (int h = 0; h < 4; ++h)
#pragma unroll
    for (int ni = 0; ni < 4; ++ni)
#pragma unroll
    for (int r = 0; r < 4; ++r) {
        int row = n0 + rw + (lane >> 4) * 4 + r;
        atomicAdd(&x0[(size_t)row * 256 + h * 64 + ni * 16 + fr], oacc[h][ni][r]);
    }
}

// ---------------- invariants ----------------
__global__ void invar_kernel(const float* __restrict__ x0, const float* __restrict__ x12,
                             float* __restrict__ inv) {
    int n = blockIdx.x, t = threadIdx.x;
    inv[(size_t)n * F_ + t] = x0[(size_t)n * D0_ + t];
    if (t < 128) {
        const float* p = x12 + (size_t)n * X12W + t * 3;
        inv[(size_t)n * F_ + 256 + t] = sqrtf(p[0]*p[0] + p[1]*p[1] + p[2]*p[2]);
    }
    if (t < 32) {
        const float* p = x12 + (size_t)n * X12W + 384 + t * 5;
        inv[(size_t)n * F_ + 384 + t] =
            sqrtf(p[0]*p[0] + p[1]*p[1] + p[2]*p[2] + p[3]*p[3] + p[4]*p[4]);
    }
}

__global__ void v1_kernel(const float* __restrict__ x12, const float* __restrict__ W,
                          float* __restrict__ Vflat) {
    int m = blockIdx.x, t = threadIdx.x;
    __shared__ float sh[384];
    sh[t] = x12[(size_t)m * X12W + t];
    __syncthreads();
    int e = t / 3, c = t % 3;
    float acc = 0.f;
#pragma unroll 4
    for (int d = 0; d < 128; ++d)
        acc = fmaf(sh[d * 3 + c], W[d * 128 + e], acc);
    Vflat[(size_t)m * X12W + t] = acc;
}

__global__ void v2_kernel(const float* __restrict__ x12, const float* __restrict__ W,
                          float* __restrict__ Vflat) {
    int m = blockIdx.x, t = threadIdx.x;
    __shared__ float sh[160];
    if (t < 160) sh[t] = x12[(size_t)m * X12W + 384 + t];
    __syncthreads();
    if (t < 160) {
        int e = t / 5, c = t % 5;
        float acc = 0.f;
#pragma unroll 4
        for (int d = 0; d < 32; ++d)
            acc = fmaf(sh[d * 5 + c], W[d * 32 + e], acc);
        Vflat[(size_t)m * X12W + 384 + t] = acc;
    }
}

__global__ void gate_kernel(const float* __restrict__ g, float* __restrict__ x12) {
    int idx = blockIdx.x * 256 + threadIdx.x;
    if (idx >= N_ * X12W) return;
    int n = idx / X12W, j = idx % X12W;
    float gv = (j < 384) ? g[n * 160 + j / 3] : g[n * 160 + 128 + (j - 384) / 5];
    x12[idx] *= gv;
}

extern "C" void kernel_launch(void* const* d_in, const int* in_sizes, int n_in,
                              void* d_out, int out_size, void* d_ws, size_t ws_size,
                              hipStream_t stream) {
    const float* x    = (const float*)d_in[0];
    const float* pos  = (const float*)d_in[1];
    const float* embW = (const float*)d_in[2];
    const float* embB = (const float*)d_in[3];
    const float* Wq   = (const float*)d_in[4];
    const float* Wk   = (const float*)d_in[5];
    const float* Wv0  = (const float*)d_in[6];
    const float* Wv1  = (const float*)d_in[7];
    const float* Wv2  = (const float*)d_in[8];
    const float* Ws1  = (const float*)d_in[9];
    const float* Ws2  = (const float*)d_in[10];
    const float* Wffa = (const float*)d_in[11];
    const float* Wffb = (const float*)d_in[12];
    const float* Wg   = (const float*)d_in[13];
    const float* outW = (const float*)d_in[14];
    const float* outB = (const float*)d_in[15];
    float* out = (float*)d_out;

    const size_t NN = (size_t)N_ * N_;
    float* p = (float*)d_ws;
    float* x0    = p; p += N_ * D0_;
    float* x12   = p; p += N_ * X12W;
    float* inv   = p; p += N_ * F_;
    float* q     = p; p += N_ * D0_;
    float* k     = p; p += N_ * D0_;
    float* v0    = p; p += N_ * D0_;
    float* Vflat = p; p += N_ * X12W;
    float* s1    = p; p += N_ * D1_;
    float* s2    = p; p += N_ * D2_;
    float* fft   = p; p += N_ * 512;
    float* gm    = p; p += N_ * 160;
    float* Macc  = p; p += 3 * N_ * 128 + 5 * N_ * 32;
    float* rsm   = p; p += H_ * N_;
    float* rsl   = p; p += H_ * N_;
    u16* ub   = (u16*)p;
    u16* amb  = ub; ub += NN;            // head-mean attention bf16 (8 MB)
    u16* U    = ub; ub += 3 * NN;        // unit vectors (24 MB)
    u16* v0T  = ub; ub += D0_ * N_;
    u16* s1T  = ub; ub += D1_ * N_;
    u16* s2T  = ub; ub += D2_ * N_;
    u16* VflatT = ub; ub += X12W * N_;

    hipMemsetAsync(x12, 0, (size_t)N_ * X12W * sizeof(float), stream);
    ucompute_kernel<<<(N_ * N_) / 256, 256, 0, stream>>>(pos, U);

    mfma_gemm<B_NN, EPI_STORE><<<dim3(4, 32), 256, 0, stream>>>(
        x, 118, embW, 256, embB, x0, 256, N_, 118, 256, 1.f, 118);

    for (int l = 0; l < L_; ++l) {
        const float* Wq_l   = Wq   + (size_t)l * F_ * 256;
        const float* Wk_l   = Wk   + (size_t)l * F_ * 256;
        const float* Wv0_l  = Wv0  + (size_t)l * 256 * 256;
        const float* Wv1_l  = Wv1  + (size_t)l * 128 * 128;
        const float* Wv2_l  = Wv2  + (size_t)l * 32 * 32;
        const float* Ws1_l  = Ws1  + (size_t)l * 256 * 128;
        const float* Ws2_l  = Ws2  + (size_t)l * 256 * 32;
        const float* Wffa_l = Wffa + (size_t)l * 256 * 512;
        const float* Wffb_l = Wffb + (size_t)l * 512 * 256;
        const float* Wg_l   = Wg   + (size_t)l * F_ * 160;

        hipMemsetAsync(Macc, 0, (3 * N_ * 128 + 5 * N_ * 32) * sizeof(float), stream);
        invar_kernel<<<N_, 256, 0, stream>>>(x0, x12, inv);
        mfma_gemm<B_NN, EPI_STORE><<<dim3(4, 32), 256, 0, stream>>>(
            inv, F_, Wq_l, 256, nullptr, q, 256, N_, F_, 256, 1.f, F_);
        mfma_gemm<B_NN, EPI_STORE><<<dim3(4, 32), 256, 0, stream>>>(
            inv, F_, Wk_l, 256, nullptr, k, 256, N_, F_, 256, 1.f, F_);
        mfma_gemm<B_NN, EPI_STORE><<<dim3(4, 32), 256, 0, stream>>>(
            x0, 256, Wv0_l, 256, nullptr, v0, 256, N_, 256, 256, 1.f, 256);
        mfma_gemm<B_NN, EPI_STORE><<<dim3(2, 32), 256, 0, stream>>>(
            x0, 256, Ws1_l, 128, nullptr, s1, 128, N_, 256, 128, 1.f, 256);
        mfma_gemm<B_NN, EPI_STORE><<<dim3(1, 32), 256, 0, stream>>>(
            x0, 256, Ws2_l, 32, nullptr, s2, 32, N_, 256, 32, 1.f, 256);
        v1_kernel<<<N_, 384, 0, stream>>>(x12, Wv1_l, Vflat);
        v2_kernel<<<N_, 192, 0, stream>>>(x12, Wv2_l, Vflat);

        transpose_bf16<<<dim3(4, 32), 256, 0, stream>>>(v0, v0T, N_, 256);
        transpose_bf16<<<dim3(2, 32), 256, 0, stream>>>(s1, s1T, N_, 128);
        transpose_bf16<<<dim3(1, 32), 256, 0, stream>>>(s2, s2T, N_, 32);
        transpose_bf16<<<dim3(9, 32), 256, 0, stream>>>(Vflat, VflatT, N_, X12W);

        // flash-style attention: no S materialization
        attn_pass1<<<dim3(32, 4), 256, 0, stream>>>(q, k, rsm, rsl);
        attn_pass2<<<dim3(32, 4), 256, 0, stream>>>(q, k, v0T, rsm, rsl, amb, x0);

        // agg1+agg2: x12 += am @ Vflat
        aggP<3><<<dim3(3, 32, 4), 256, 0, stream>>>(
            amb, N_, VflatT, N_, x12, X12W, N_, X12W, 512, 4);
        // fused mix
        mixf_kernel<1><<<dim3(8, 32), 256, 0, stream>>>(amb, U, s1T, Macc);
        mixf_kernel<2><<<dim3(8, 32), 256, 0, stream>>>(amb, U, s2T, Macc);
        mix_combine<<<(N_ * X12W + 255) / 256, 256, 0, stream>>>(Macc, x12);

        mfma_gemm<B_NN, EPI_SILU><<<dim3(8, 32), 256, 0, stream>>>(
            x0, 256, Wffa_l, 512, nullptr, fft, 512, N_, 256, 512, 1.f, 256);
        mfma_gemm<B_NN, EPI_ACCUM><<<dim3(4, 32), 256, 0, stream>>>(
            fft, 512, Wffb_l, 256, nullptr, x0, 256, N_, 512, 256, 1.f, 512);

        invar_kernel<<<N_, 256, 0, stream>>>(x0, x12, inv);
        mfma_gemm<B_NN, EPI_SIGMOID><<<dim3(3, 32), 256, 0, stream>>>(
            inv, F_, Wg_l, 160, nullptr, gm, 160, N_, F_, 160, 1.f, F_);
        gate_kernel<<<(N_ * X12W + 255) / 256, 256, 0, stream>>>(gm, x12);
    }

    mfma_gemm<B_NN, EPI_STORE><<<dim3(1, 32), 256, 0, stream>>>(
        x0, 256, outW, NC_, outB, out, NC_, N_, 256, NC_, 1.f, 256);
}

// Round 12
// 1562.689 us; speedup vs baseline: 1.1795x; 1.1795x over previous
//
#include <hip/hip_runtime.h>
#include <math.h>

#define N_    2048
#define D0_   256
#define D1_   128
#define D2_   32
#define F_    416
#define H_    4
#define DH_   64
#define L_    4
#define NC_   10
#define C2_   1.7320508075688772f
#define X12W  544

typedef unsigned short u16;
typedef __attribute__((ext_vector_type(8))) short short8v;
typedef __attribute__((ext_vector_type(4))) float f32x4;

union U8 { u16 u[8]; short8v v; };

__device__ __forceinline__ u16 f2bf(float f) {
    union { float f; unsigned int u; } x; x.f = f;
    unsigned int r = x.u + 0x7FFFu + ((x.u >> 16) & 1u);
    return (u16)(r >> 16);
}
__device__ __forceinline__ float bf2f(u16 u) {
    union { float f; unsigned int u; } x; x.u = ((unsigned int)u) << 16;
    return x.f;
}
__device__ __forceinline__ f32x4 mfma16(short8v a, short8v b, f32x4 c) {
    return __builtin_amdgcn_mfma_f32_16x16x32_bf16(a, b, c, 0, 0, 0);
}

// ================= MFMA GEMM (dense layers) =================
enum { B_NN = 0, B_NT = 1 };
enum { EPI_STORE = 0, EPI_SILU = 1, EPI_SIGMOID = 2, EPI_ACCUM = 3, EPI_ATOMIC = 4 };

template<int BLAY, int EPI>
__global__ __launch_bounds__(256) void mfma_gemm(
    const float* __restrict__ A, int lda,
    const float* __restrict__ B, int ldb,
    const float* __restrict__ bias,
    float* __restrict__ C, int ldc,
    int M, int K, int Nn, float scale, int kchunk)
{
    __shared__ __align__(16) u16 As[64][40];
    __shared__ __align__(16) u16 Bs[64][40];
    const int t = threadIdx.x;
    const int bm = blockIdx.y * 64, bn = blockIdx.x * 64;
    const int lane = t & 63, w = t >> 6;
    const int r0 = (w >> 1) * 32, c0 = (w & 1) * 32;
    const int fr = lane & 15, fk = (lane >> 4) * 8;
    const int ml = t >> 2, k8 = (t & 3) * 8;
    const int kbeg = blockIdx.z * kchunk;
    const int kend = (kbeg + kchunk < K) ? kbeg + kchunk : K;
    f32x4 acc[2][2] = {};

    for (int k0 = kbeg; k0 < kend; k0 += 32) {
        {
            U8 u;
            if (((lda & 3) == 0) && (k0 + 32 <= kend)) {
                const float* ap = A + (size_t)(bm + ml) * lda + k0 + k8;
                float4 a0 = *(const float4*)ap;
                float4 a1 = *(const float4*)(ap + 4);
                u.u[0]=f2bf(a0.x); u.u[1]=f2bf(a0.y); u.u[2]=f2bf(a0.z); u.u[3]=f2bf(a0.w);
                u.u[4]=f2bf(a1.x); u.u[5]=f2bf(a1.y); u.u[6]=f2bf(a1.z); u.u[7]=f2bf(a1.w);
            } else {
#pragma unroll
                for (int j = 0; j < 8; ++j) {
                    int kk = k0 + k8 + j;
                    u.u[j] = f2bf(kk < kend ? A[(size_t)(bm + ml) * lda + kk] : 0.f);
                }
            }
            *(short8v*)&As[ml][k8] = u.v;
        }
        {
            U8 u;
            if (BLAY == B_NT) {
#pragma unroll
                for (int j = 0; j < 8; ++j) {
                    int kk = k0 + k8 + j;
                    u.u[j] = f2bf((kk < kend && bn + ml < Nn)
                                  ? B[(size_t)(bn + ml) * ldb + kk] : 0.f);
                }
            } else {
                int nc = bn + ml;
#pragma unroll
                for (int j = 0; j < 8; ++j) {
                    int kk = k0 + k8 + j;
                    u.u[j] = f2bf((kk < kend && nc < Nn) ? B[(size_t)kk * ldb + nc] : 0.f);
                }
            }
            *(short8v*)&Bs[ml][k8] = u.v;
        }
        __syncthreads();
        short8v a0 = *(const short8v*)&As[r0 + fr][fk];
        short8v a1 = *(const short8v*)&As[r0 + 16 + fr][fk];
        short8v b0 = *(const short8v*)&Bs[c0 + fr][fk];
        short8v b1 = *(const short8v*)&Bs[c0 + 16 + fr][fk];
        acc[0][0] = mfma16(a0, b0, acc[0][0]);
        acc[0][1] = mfma16(a0, b1, acc[0][1]);
        acc[1][0] = mfma16(a1, b0, acc[1][0]);
        acc[1][1] = mfma16(a1, b1, acc[1][1]);
        __syncthreads();
    }
#pragma unroll
    for (int mi = 0; mi < 2; ++mi)
#pragma unroll
    for (int ni = 0; ni < 2; ++ni)
#pragma unroll
    for (int r = 0; r < 4; ++r) {
        int row = bm + r0 + mi * 16 + ((lane >> 4) << 2) + r;
        int col = bn + c0 + ni * 16 + fr;
        if (col >= Nn) continue;
        float v = acc[mi][ni][r];
        float* cp = C + (size_t)row * ldc + col;
        if (EPI == EPI_STORE)   *cp = v * scale + (bias ? bias[col] : 0.f);
        if (EPI == EPI_SILU)    *cp = v / (1.f + expf(-v));
        if (EPI == EPI_SIGMOID) *cp = 1.f / (1.f + expf(-v));
        if (EPI == EPI_ACCUM)   *cp += v;
        if (EPI == EPI_ATOMIC)  atomicAdd(cp, v);
    }
}

// --------- transpose: in [R][C] f32 -> out [C][R] bf16 ---------
__global__ __launch_bounds__(256) void transpose_bf16(
    const float* __restrict__ in, u16* __restrict__ outT, int R, int C)
{
    __shared__ float tile[64][65];
    const int br = blockIdx.y * 64, bc = blockIdx.x * 64;
    const int t = threadIdx.x, lc = t & 63, q = t >> 6;
#pragma unroll 4
    for (int r = 0; r < 16; ++r) {
        int row = br + q * 16 + r, col = bc + lc;
        tile[q * 16 + r][lc] = (col < C) ? in[(size_t)row * C + col] : 0.f;
    }
    __syncthreads();
#pragma unroll 4
    for (int r = 0; r < 16; ++r) {
        int orow = bc + q * 16 + r;
        int ocol = br + lc;
        if (orow < C) outT[(size_t)orow * R + ocol] = f2bf(tile[lc][q * 16 + r]);
    }
}

// ============ aggP: bf16 A [M][K] @ bf16 BT [Nn][K] -> atomic C ============
template<int NB>
__global__ __launch_bounds__(256) void aggP(
    const u16* __restrict__ A, int lda,
    const u16* __restrict__ BT, int ldk,
    float* __restrict__ C, int ldc,
    int K, int Nn, int kchunk, int zk)
{
    __shared__ __align__(16) u16 As[64][40];
    __shared__ __align__(16) u16 Bs[NB][64][40];
    const int t = threadIdx.x;
    const int bm = blockIdx.y * 64, bn0 = blockIdx.x * 64 * NB;
    const int kz = blockIdx.z % zk;
    const int lane = t & 63, w = t >> 6;
    const int r0 = (w >> 1) * 32, c0 = (w & 1) * 32;
    const int fr = lane & 15, fk = (lane >> 4) * 8;
    const int ml = t >> 2, k8 = (t & 3) * 8;
    const int kbeg = kz * kchunk;
    const int kend = (kbeg + kchunk < K) ? kbeg + kchunk : K;
    f32x4 acc[NB][2][2] = {};

    for (int k0 = kbeg; k0 < kend; k0 += 32) {
        *(short8v*)&As[ml][k8] = *(const short8v*)(A + (size_t)(bm + ml) * lda + k0 + k8);
#pragma unroll
        for (int nb = 0; nb < NB; ++nb) {
            int nc = bn0 + nb * 64 + ml;
            short8v z = {};
            *(short8v*)&Bs[nb][ml][k8] = (nc < Nn)
                ? *(const short8v*)(BT + (size_t)nc * ldk + k0 + k8) : z;
        }
        __syncthreads();
        short8v a0 = *(const short8v*)&As[r0 + fr][fk];
        short8v a1 = *(const short8v*)&As[r0 + 16 + fr][fk];
#pragma unroll
        for (int nb = 0; nb < NB; ++nb) {
            short8v b0 = *(const short8v*)&Bs[nb][c0 + fr][fk];
            short8v b1 = *(const short8v*)&Bs[nb][c0 + 16 + fr][fk];
            acc[nb][0][0] = mfma16(a0, b0, acc[nb][0][0]);
            acc[nb][0][1] = mfma16(a0, b1, acc[nb][0][1]);
            acc[nb][1][0] = mfma16(a1, b0, acc[nb][1][0]);
            acc[nb][1][1] = mfma16(a1, b1, acc[nb][1][1]);
        }
        __syncthreads();
    }
#pragma unroll
    for (int nb = 0; nb < NB; ++nb)
#pragma unroll
    for (int mi = 0; mi < 2; ++mi)
#pragma unroll
    for (int ni = 0; ni < 2; ++ni)
#pragma unroll
    for (int r = 0; r < 4; ++r) {
        int row = bm + r0 + mi * 16 + ((lane >> 4) << 2) + r;
        int col = bn0 + nb * 64 + c0 + ni * 16 + fr;
        if (col >= Nn) continue;
        atomicAdd(C + (size_t)row * ldc + col, acc[nb][mi][ni][r]);
    }
}

// ---------------- u precompute ----------------
__global__ void ucompute_kernel(const float* __restrict__ pos, u16* __restrict__ U) {
    int idx = blockIdx.x * 256 + threadIdx.x;
    int n = idx >> 11, m = idx & (N_ - 1);
    float rx = pos[m * 3 + 0] - pos[n * 3 + 0];
    float ry = pos[m * 3 + 1] - pos[n * 3 + 1];
    float rz = pos[m * 3 + 2] - pos[n * 3 + 2];
    float d2 = rx * rx + ry * ry + rz * rz;
    bool valid = d2 > 1e-12f;
    float rinv = valid ? rsqrtf(d2) : 0.f;
    size_t base = (size_t)n * N_ + m;
    const size_t CS = (size_t)N_ * N_;
    U[base]          = f2bf(rx * rinv);
    U[base + CS]     = f2bf(ry * rinv);
    U[base + 2 * CS] = f2bf(rz * rinv);
}

// ============ fused mix: all channels of one degree, one col-tile per block ============
// DEG=1: 3 channels, grid (8 ks, 32, 2 ct), kchunk 256.
// DEG=2: 5 channels, grid (16 ks, 32, 1),  kchunk 128.
template<int DEG>
__global__ __launch_bounds__(256) void mixf_kernel(
    const u16* __restrict__ amb, const u16* __restrict__ U,
    const u16* __restrict__ BT, float* __restrict__ Macc, int kchunk)
{
    constexpr int NCH = (DEG == 1) ? 3 : 5;
    const int bm = blockIdx.y * 64;
    const int colbase = blockIdx.z * 64;
    const size_t CS = (size_t)N_ * N_;
    __shared__ __align__(16) u16 As[NCH][64][40];
    __shared__ __align__(16) u16 Bs[64][40];
    const int t = threadIdx.x, lane = t & 63, w = t >> 6;
    const int r0 = (w >> 1) * 32, c0 = (w & 1) * 32;
    const int fr = lane & 15, fk = (lane >> 4) * 8;
    const int ml = t >> 2, k8 = (t & 3) * 8;
    const int kbeg = blockIdx.x * kchunk, kend = kbeg + kchunk;
    f32x4 acc[NCH][2][2] = {};

    for (int m0 = kbeg; m0 < kend; m0 += 32) {
        const size_t off = (size_t)(bm + ml) * N_ + m0 + k8;
        U8 am8; am8.v = *(const short8v*)(amb + off);
        U8 xv, yv, zv;
        xv.v = *(const short8v*)(U + off);
        yv.v = *(const short8v*)(U + CS + off);
        zv.v = *(const short8v*)(U + 2 * CS + off);
        if (DEG == 1) {
            U8 o0, o1, o2;
#pragma unroll
            for (int j = 0; j < 8; ++j) {
                float a = bf2f(am8.u[j]);
                o0.u[j] = f2bf(a * bf2f(xv.u[j]));
                o1.u[j] = f2bf(a * bf2f(yv.u[j]));
                o2.u[j] = f2bf(a * bf2f(zv.u[j]));
            }
            *(short8v*)&As[0][ml][k8] = o0.v;
            *(short8v*)&As[1][ml][k8] = o1.v;
            *(short8v*)&As[2][ml][k8] = o2.v;
        } else {
            U8 o[5];
#pragma unroll
            for (int j = 0; j < 8; ++j) {
                float a = bf2f(am8.u[j]);
                float ux = bf2f(xv.u[j]), uy = bf2f(yv.u[j]), uz = bf2f(zv.u[j]);
                o[0].u[j] = f2bf(a * C2_ * ux * uy);
                o[1].u[j] = f2bf(a * C2_ * uy * uz);
                o[2].u[j] = f2bf((ux*ux + uy*uy + uz*uz > 0.5f)
                                 ? a * 0.5f * (3.f * uz * uz - 1.f) : 0.f);
                o[3].u[j] = f2bf(a * C2_ * ux * uz);
                o[4].u[j] = f2bf(a * 0.5f * C2_ * (ux * ux - uy * uy));
            }
#pragma unroll
            for (int c = 0; c < 5; ++c) *(short8v*)&As[c][ml][k8] = o[c].v;
        }
        {
            int nc = colbase + ml;
            short8v z = {};
            *(short8v*)&Bs[ml][k8] = (DEG == 1 || nc < 32)
                ? *(const short8v*)(BT + (size_t)nc * N_ + m0 + k8) : z;
        }
        __syncthreads();
        short8v b0 = *(const short8v*)&Bs[c0 + fr][fk];
        short8v b1 = *(const short8v*)&Bs[c0 + 16 + fr][fk];
#pragma unroll
        for (int c = 0; c < NCH; ++c) {
            short8v a0 = *(const short8v*)&As[c][r0 + fr][fk];
            short8v a1 = *(const short8v*)&As[c][r0 + 16 + fr][fk];
            acc[c][0][0] = mfma16(a0, b0, acc[c][0][0]);
            acc[c][0][1] = mfma16(a0, b1, acc[c][0][1]);
            acc[c][1][0] = mfma16(a1, b0, acc[c][1][0]);
            acc[c][1][1] = mfma16(a1, b1, acc[c][1][1]);
        }
        __syncthreads();
    }
#pragma unroll
    for (int c = 0; c < NCH; ++c)
#pragma unroll
    for (int mi = 0; mi < 2; ++mi)
#pragma unroll
    for (int ni = 0; ni < 2; ++ni)
#pragma unroll
    for (int r = 0; r < 4; ++r) {
        int row = bm + r0 + mi * 16 + ((lane >> 4) << 2) + r;
        int col = colbase + c0 + ni * 16 + fr;
        float v = acc[c][mi][ni][r];
        if (DEG == 1)
            atomicAdd(&Macc[(size_t)c * N_ * 128 + (size_t)row * 128 + col], v);
        else if (col < 32)
            atomicAdd(&Macc[(size_t)3 * N_ * 128 + (size_t)c * N_ * 32
                            + (size_t)row * 32 + col], v);
    }
}

// -------- combine: x12 += Macc --------
__global__ void mix_combine(const float* __restrict__ Macc, float* __restrict__ x12) {
    int idx = blockIdx.x * 256 + threadIdx.x;
    if (idx >= N_ * X12W) return;
    int n = idx / X12W, j = idx % X12W;
    float v;
    if (j < 384) {
        int e = j / 3, c = j - 3 * e;
        v = Macc[(size_t)c * N_ * 128 + (size_t)n * 128 + e];
    } else {
        int jj = j - 384;
        int e = jj / 5, c = jj - 5 * e;
        v = Macc[(size_t)3 * N_ * 128 + (size_t)c * N_ * 32 + (size_t)n * 32 + e];
    }
    x12[idx] += v;
}

// ============ attention pass 1: partial online max/sum, m-split ============
// grid (32 rowblocks, 4 heads, 8 msplits of 256). q held in registers.
__global__ __launch_bounds__(256) void attn_pass1(
    const float* __restrict__ q, const float* __restrict__ k,
    float* __restrict__ pm, float* __restrict__ pl)
{
    const int n0 = blockIdx.x * 64, h = blockIdx.y, ms = blockIdx.z;
    __shared__ __align__(16) u16 kt[64][72];
    const int t = threadIdx.x, lane = t & 63, w = t >> 6;
    const int fr = lane & 15, fk = (lane >> 4) * 8;
    const int sr = t >> 2, sc = (t & 3) * 16;
    const int rw = w * 16;
    U8 qa0, qa1;
    {
        const float* qp = q + (size_t)(n0 + rw + fr) * 256 + h * 64;
#pragma unroll
        for (int j = 0; j < 8; ++j) {
            qa0.u[j] = f2bf(qp[fk + j]);
            qa1.u[j] = f2bf(qp[32 + fk + j]);
        }
    }
    float mrun[4] = {-1e30f, -1e30f, -1e30f, -1e30f};
    float lrun[4] = {};

    for (int mt = 0; mt < 4; ++mt) {
        const int m0 = ms * 256 + mt * 64;
        __syncthreads();
        {
            const float* kp = k + (size_t)(m0 + sr) * 256 + h * 64 + sc;
            U8 u0, u1;
#pragma unroll
            for (int j = 0; j < 8; ++j) { u0.u[j] = f2bf(kp[j]); u1.u[j] = f2bf(kp[8 + j]); }
            *(short8v*)&kt[sr][sc] = u0.v;
            *(short8v*)&kt[sr][sc + 8] = u1.v;
        }
        __syncthreads();
        f32x4 sacc[4] = {};
#pragma unroll
        for (int ni = 0; ni < 4; ++ni) {
            short8v b0 = *(const short8v*)&kt[ni * 16 + fr][fk];
            short8v b1 = *(const short8v*)&kt[ni * 16 + fr][32 + fk];
            sacc[ni] = mfma16(qa1.v, b1, mfma16(qa0.v, b0, sacc[ni]));
        }
#pragma unroll
        for (int r = 0; r < 4; ++r) {
            float tm = -1e30f;
#pragma unroll
            for (int ni = 0; ni < 4; ++ni) tm = fmaxf(tm, sacc[ni][r] * 0.125f);
            tm = fmaxf(tm, __shfl_xor(tm, 1));
            tm = fmaxf(tm, __shfl_xor(tm, 2));
            tm = fmaxf(tm, __shfl_xor(tm, 4));
            tm = fmaxf(tm, __shfl_xor(tm, 8));
            float mn = fmaxf(mrun[r], tm);
            float ts = 0.f;
#pragma unroll
            for (int ni = 0; ni < 4; ++ni) ts += expf(sacc[ni][r] * 0.125f - mn);
            ts += __shfl_xor(ts, 1);
            ts += __shfl_xor(ts, 2);
            ts += __shfl_xor(ts, 4);
            ts += __shfl_xor(ts, 8);
            lrun[r] = lrun[r] * expf(mrun[r] - mn) + ts;
            mrun[r] = mn;
        }
    }
    if (fr == 0) {
#pragma unroll
        for (int r = 0; r < 4; ++r) {
            int row = n0 + rw + (lane >> 4) * 4 + r;
            pm[(size_t)(h * 8 + ms) * N_ + row] = mrun[r];
            pl[(size_t)(h * 8 + ms) * N_ + row] = lrun[r];
        }
    }
}

// ------- merge 8 partials -> rsm (row max), rsl (1/row sum) -------
__global__ void attn_combine(const float* __restrict__ pm, const float* __restrict__ pl,
                             float* __restrict__ rsm, float* __restrict__ rsl) {
    int idx = blockIdx.x * 256 + threadIdx.x;   // H*N entries
    if (idx >= H_ * N_) return;
    int h = idx >> 11, row = idx & (N_ - 1);
    float m = -1e30f;
#pragma unroll
    for (int s = 0; s < 8; ++s)
        m = fmaxf(m, pm[(size_t)(h * 8 + s) * N_ + row]);
    float l = 0.f;
#pragma unroll
    for (int s = 0; s < 8; ++s)
        l += pl[(size_t)(h * 8 + s) * N_ + row]
             * expf(pm[(size_t)(h * 8 + s) * N_ + row] - m);
    rsm[(size_t)h * N_ + row] = m;
    rsl[(size_t)h * N_ + row] = 1.f / l;
}

// ============ attention pass 2: P on the fly -> amb + x0 += P@V ============
// grid (32 rowblocks, 16 m-splits of 128). q in registers; LDS = kt+vt+Plds.
__global__ __launch_bounds__(256) void attn_pass2(
    const float* __restrict__ q, const float* __restrict__ k,
    const u16* __restrict__ v0T,
    const float* __restrict__ rsm, const float* __restrict__ rsl,
    u16* __restrict__ amb, float* __restrict__ x0)
{
    const int n0 = blockIdx.x * 64, mbase = blockIdx.y * 128;
    __shared__ __align__(16) u16 kt[64][72];
    __shared__ __align__(16) u16 vt[64][72];
    __shared__ __align__(16) u16 Plds[4][16][72];
    const int t = threadIdx.x, lane = t & 63, w = t >> 6;
    const int fr = lane & 15, fk = (lane >> 4) * 8;
    const int sr = t >> 2, sc = (t & 3) * 16;
    const int rw = w * 16;
    U8 qa[4][2];
#pragma unroll
    for (int h = 0; h < 4; ++h) {
        const float* qp = q + (size_t)(n0 + rw + fr) * 256 + h * 64;
#pragma unroll
        for (int j = 0; j < 8; ++j) {
            qa[h][0].u[j] = f2bf(qp[fk + j]);
            qa[h][1].u[j] = f2bf(qp[32 + fk + j]);
        }
    }
    f32x4 oacc[4][4] = {};

    for (int mt = 0; mt < 2; ++mt) {
        const int m0 = mbase + mt * 64;
        f32x4 amac[4] = {};
#pragma unroll
        for (int h = 0; h < 4; ++h) {
            __syncthreads();
            {
                const float* kp = k + (size_t)(m0 + sr) * 256 + h * 64 + sc;
                U8 u0, u1;
#pragma unroll
                for (int j = 0; j < 8; ++j) { u0.u[j] = f2bf(kp[j]); u1.u[j] = f2bf(kp[8 + j]); }
                *(short8v*)&kt[sr][sc] = u0.v;
                *(short8v*)&kt[sr][sc + 8] = u1.v;
                *(short8v*)&vt[sr][sc] =
                    *(const short8v*)(v0T + (size_t)(h * 64 + sr) * N_ + m0 + sc);
                *(short8v*)&vt[sr][sc + 8] =
                    *(const short8v*)(v0T + (size_t)(h * 64 + sr) * N_ + m0 + sc + 8);
            }
            __syncthreads();
            float mf[4], lf[4];
#pragma unroll
            for (int r = 0; r < 4; ++r) {
                int row = n0 + rw + (lane >> 4) * 4 + r;
                mf[r] = rsm[(size_t)h * N_ + row];
                lf[r] = rsl[(size_t)h * N_ + row];
            }
#pragma unroll
            for (int ni = 0; ni < 4; ++ni) {
                short8v b0 = *(const short8v*)&kt[ni * 16 + fr][fk];
                short8v b1 = *(const short8v*)&kt[ni * 16 + fr][32 + fk];
                f32x4 sacc = {};
                sacc = mfma16(qa[h][1].v, b1, mfma16(qa[h][0].v, b0, sacc));
#pragma unroll
                for (int r = 0; r < 4; ++r) {
                    float pv = expf(sacc[r] * 0.125f - mf[r]) * lf[r];
                    amac[ni][r] += 0.25f * pv;
                    Plds[w][(lane >> 4) * 4 + r][ni * 16 + fr] = f2bf(pv);
                }
            }
            __syncthreads();
            short8v pa0 = *(const short8v*)&Plds[w][fr][fk];
            short8v pa1 = *(const short8v*)&Plds[w][fr][32 + fk];
#pragma unroll
            for (int ni = 0; ni < 4; ++ni) {
                short8v b0 = *(const short8v*)&vt[ni * 16 + fr][fk];
                short8v b1 = *(const short8v*)&vt[ni * 16 + fr][32 + fk];
                oacc[h][ni] = mfma16(pa1, b1, mfma16(pa0, b0, oacc[h][ni]));
            }
        }
#pragma unroll
        for (int ni = 0; ni < 4; ++ni)
#pragma unroll
        for (int r = 0; r < 4; ++r) {
            int row = n0 + rw + (lane >> 4) * 4 + r;
            amb[(size_t)row * N_ + m0 + ni * 16 + fr] = f2bf(amac[ni][r]);
        }
    }
#pragma unroll
    for (int h = 0; h < 4; ++h)
#pragma unroll
    for (int ni = 0; ni < 4; ++ni)
#pragma unroll
    for (int r = 0; r < 4; ++r) {
        int row = n0 + rw + (lane >> 4) * 4 + r;
        atomicAdd(&x0[(size_t)row * 256 + h * 64 + ni * 16 + fr], oacc[h][ni][r]);
    }
}

// ---------------- invariants ----------------
__global__ void invar_kernel(const float* __restrict__ x0, const float* __restrict__ x12,
                             float* __restrict__ inv) {
    int n = blockIdx.x, t = threadIdx.x;
    inv[(size_t)n * F_ + t] = x0[(size_t)n * D0_ + t];
    if (t < 128) {
        const float* p = x12 + (size_t)n * X12W + t * 3;
        inv[(size_t)n * F_ + 256 + t] = sqrtf(p[0]*p[0] + p[1]*p[1] + p[2]*p[2]);
    }
    if (t < 32) {
        const float* p = x12 + (size_t)n * X12W + 384 + t * 5;
        inv[(size_t)n * F_ + 384 + t] =
            sqrtf(p[0]*p[0] + p[1]*p[1] + p[2]*p[2] + p[3]*p[3] + p[4]*p[4]);
    }
}

__global__ void v1_kernel(const float* __restrict__ x12, const float* __restrict__ W,
                          float* __restrict__ Vflat) {
    int m = blockIdx.x, t = threadIdx.x;
    __shared__ float sh[384];
    sh[t] = x12[(size_t)m * X12W + t];
    __syncthreads();
    int e = t / 3, c = t % 3;
    float acc = 0.f;
#pragma unroll 4
    for (int d = 0; d < 128; ++d)
        acc = fmaf(sh[d * 3 + c], W[d * 128 + e], acc);
    Vflat[(size_t)m * X12W + t] = acc;
}

__global__ void v2_kernel(const float* __restrict__ x12, const float* __restrict__ W,
                          float* __restrict__ Vflat) {
    int m = blockIdx.x, t = threadIdx.x;
    __shared__ float sh[160];
    if (t < 160) sh[t] = x12[(size_t)m * X12W + 384 + t];
    __syncthreads();
    if (t < 160) {
        int e = t / 5, c = t % 5;
        float acc = 0.f;
#pragma unroll 4
        for (int d = 0; d < 32; ++d)
            acc = fmaf(sh[d * 5 + c], W[d * 32 + e], acc);
        Vflat[(size_t)m * X12W + 384 + t] = acc;
    }
}

__global__ void gate_kernel(const float* __restrict__ g, float* __restrict__ x12) {
    int idx = blockIdx.x * 256 + threadIdx.x;
    if (idx >= N_ * X12W) return;
    int n = idx / X12W, j = idx % X12W;
    float gv = (j < 384) ? g[n * 160 + j / 3] : g[n * 160 + 128 + (j - 384) / 5];
    x12[idx] *= gv;
}

extern "C" void kernel_launch(void* const* d_in, const int* in_sizes, int n_in,
                              void* d_out, int out_size, void* d_ws, size_t ws_size,
                              hipStream_t stream) {
    const float* x    = (const float*)d_in[0];
    const float* pos  = (const float*)d_in[1];
    const float* embW = (const float*)d_in[2];
    const float* embB = (const float*)d_in[3];
    const float* Wq   = (const float*)d_in[4];
    const float* Wk   = (const float*)d_in[5];
    const float* Wv0  = (const float*)d_in[6];
    const float* Wv1  = (const float*)d_in[7];
    const float* Wv2  = (const float*)d_in[8];
    const float* Ws1  = (const float*)d_in[9];
    const float* Ws2  = (const float*)d_in[10];
    const float* Wffa = (const float*)d_in[11];
    const float* Wffb = (const float*)d_in[12];
    const float* Wg   = (const float*)d_in[13];
    const float* outW = (const float*)d_in[14];
    const float* outB = (const float*)d_in[15];
    float* out = (float*)d_out;

    const size_t NN = (size_t)N_ * N_;
    float* p = (float*)d_ws;
    float* x0    = p; p += N_ * D0_;
    float* x12   = p; p += N_ * X12W;
    float* inv   = p; p += N_ * F_;
    float* q     = p; p += N_ * D0_;
    float* k     = p; p += N_ * D0_;
    float* v0    = p; p += N_ * D0_;
    float* Vflat = p; p += N_ * X12W;
    float* s1    = p; p += N_ * D1_;
    float* s2    = p; p += N_ * D2_;
    float* fft   = p; p += N_ * 512;
    float* gm    = p; p += N_ * 160;
    float* Macc  = p; p += 3 * N_ * 128 + 5 * N_ * 32;
    float* rsm   = p; p += H_ * N_;
    float* rsl   = p; p += H_ * N_;
    float* pm    = p; p += H_ * 8 * N_;
    float* pl    = p; p += H_ * 8 * N_;
    u16* ub   = (u16*)p;
    u16* amb  = ub; ub += NN;            // head-mean attention bf16 (8 MB)
    u16* U    = ub; ub += 3 * NN;        // unit vectors (24 MB)
    u16* v0T  = ub; ub += D0_ * N_;
    u16* s1T  = ub; ub += D1_ * N_;
    u16* s2T  = ub; ub += D2_ * N_;
    u16* VflatT = ub; ub += X12W * N_;

    hipMemsetAsync(x12, 0, (size_t)N_ * X12W * sizeof(float), stream);
    ucompute_kernel<<<(N_ * N_) / 256, 256, 0, stream>>>(pos, U);

    mfma_gemm<B_NN, EPI_STORE><<<dim3(4, 32), 256, 0, stream>>>(
        x, 118, embW, 256, embB, x0, 256, N_, 118, 256, 1.f, 118);

    for (int l = 0; l < L_; ++l) {
        const float* Wq_l   = Wq   + (size_t)l * F_ * 256;
        const float* Wk_l   = Wk   + (size_t)l * F_ * 256;
        const float* Wv0_l  = Wv0  + (size_t)l * 256 * 256;
        const float* Wv1_l  = Wv1  + (size_t)l * 128 * 128;
        const float* Wv2_l  = Wv2  + (size_t)l * 32 * 32;
        const float* Ws1_l  = Ws1  + (size_t)l * 256 * 128;
        const float* Ws2_l  = Ws2  + (size_t)l * 256 * 32;
        const float* Wffa_l = Wffa + (size_t)l * 256 * 512;
        const float* Wffb_l = Wffb + (size_t)l * 512 * 256;
        const float* Wg_l   = Wg   + (size_t)l * F_ * 160;

        hipMemsetAsync(Macc, 0, (3 * N_ * 128 + 5 * N_ * 32) * sizeof(float), stream);
        invar_kernel<<<N_, 256, 0, stream>>>(x0, x12, inv);
        mfma_gemm<B_NN, EPI_STORE><<<dim3(4, 32), 256, 0, stream>>>(
            inv, F_, Wq_l, 256, nullptr, q, 256, N_, F_, 256, 1.f, F_);
        mfma_gemm<B_NN, EPI_STORE><<<dim3(4, 32), 256, 0, stream>>>(
            inv, F_, Wk_l, 256, nullptr, k, 256, N_, F_, 256, 1.f, F_);
        mfma_gemm<B_NN, EPI_STORE><<<dim3(4, 32), 256, 0, stream>>>(
            x0, 256, Wv0_l, 256, nullptr, v0, 256, N_, 256, 256, 1.f, 256);
        mfma_gemm<B_NN, EPI_STORE><<<dim3(2, 32), 256, 0, stream>>>(
            x0, 256, Ws1_l, 128, nullptr, s1, 128, N_, 256, 128, 1.f, 256);
        mfma_gemm<B_NN, EPI_STORE><<<dim3(1, 32), 256, 0, stream>>>(
            x0, 256, Ws2_l, 32, nullptr, s2, 32, N_, 256, 32, 1.f, 256);
        v1_kernel<<<N_, 384, 0, stream>>>(x12, Wv1_l, Vflat);
        v2_kernel<<<N_, 192, 0, stream>>>(x12, Wv2_l, Vflat);

        transpose_bf16<<<dim3(4, 32), 256, 0, stream>>>(v0, v0T, N_, 256);
        transpose_bf16<<<dim3(2, 32), 256, 0, stream>>>(s1, s1T, N_, 128);
        transpose_bf16<<<dim3(1, 32), 256, 0, stream>>>(s2, s2T, N_, 32);
        transpose_bf16<<<dim3(9, 32), 256, 0, stream>>>(Vflat, VflatT, N_, X12W);

        // flash attention: partial pass1 -> combine -> pass2
        attn_pass1<<<dim3(32, 4, 8), 256, 0, stream>>>(q, k, pm, pl);
        attn_combine<<<(H_ * N_ + 255) / 256, 256, 0, stream>>>(pm, pl, rsm, rsl);
        attn_pass2<<<dim3(32, 16), 256, 0, stream>>>(q, k, v0T, rsm, rsl, amb, x0);

        // agg1+agg2: x12 += am @ Vflat
        aggP<3><<<dim3(3, 32, 4), 256, 0, stream>>>(
            amb, N_, VflatT, N_, x12, X12W, N_, X12W, 512, 4);
        // fused mix (512 blocks each)
        mixf_kernel<1><<<dim3(8, 32, 2), 256, 0, stream>>>(amb, U, s1T, Macc, 256);
        mixf_kernel<2><<<dim3(16, 32, 1), 256, 0, stream>>>(amb, U, s2T, Macc, 128);
        mix_combine<<<(N_ * X12W + 255) / 256, 256, 0, stream>>>(Macc, x12);

        mfma_gemm<B_NN, EPI_SILU><<<dim3(8, 32), 256, 0, stream>>>(
            x0, 256, Wffa_l, 512, nullptr, fft, 512, N_, 256, 512, 1.f, 256);
        mfma_gemm<B_NN, EPI_ACCUM><<<dim3(4, 32), 256, 0, stream>>>(
            fft, 512, Wffb_l, 256, nullptr, x0, 256, N_, 512, 256, 1.f, 512);

        invar_kernel<<<N_, 256, 0, stream>>>(x0, x12, inv);
        mfma_gemm<B_NN, EPI_SIGMOID><<<dim3(3, 32), 256, 0, stream>>>(
            inv, F_, Wg_l, 160, nullptr, gm, 160, N_, F_, 160, 1.f, F_);
        gate_kernel<<<(N_ * X12W + 255) / 256, 256, 0, stream>>>(gm, x12);
    }

    mfma_gemm<B_NN, EPI_STORE><<<dim3(1, 32), 256, 0, stream>>>(
        x0, 256, outW, NC_, outB, out, NC_, N_, 256, NC_, 1.f, 256);
}

// Round 13
// 1463.359 us; speedup vs baseline: 1.2595x; 1.0679x over previous
//
#include <hip/hip_runtime.h>
#include <math.h>

#define N_    2048
#define D0_   256
#define D1_   128
#define D2_   32
#define F_    416
#define H_    4
#define DH_   64
#define L_    4
#define NC_   10
#define C2_   1.7320508075688772f
#define X12W  544

typedef unsigned short u16;
typedef __attribute__((ext_vector_type(8))) short short8v;
typedef __attribute__((ext_vector_type(4))) float f32x4;

union U8 { u16 u[8]; short8v v; };

__device__ __forceinline__ u16 f2bf(float f) {
    union { float f; unsigned int u; } x; x.f = f;
    unsigned int r = x.u + 0x7FFFu + ((x.u >> 16) & 1u);
    return (u16)(r >> 16);
}
__device__ __forceinline__ float bf2f(u16 u) {
    union { float f; unsigned int u; } x; x.u = ((unsigned int)u) << 16;
    return x.f;
}
__device__ __forceinline__ f32x4 mfma16(short8v a, short8v b, f32x4 c) {
    return __builtin_amdgcn_mfma_f32_16x16x32_bf16(a, b, c, 0, 0, 0);
}

// ================= MFMA GEMM: f32 in (cast bf16), epilogues ===========
// blockIdx.z = h*zk + kz : h = head (A+=Ah, B+=Bh, C+=Ch), kz = K-split.
enum { B_NN = 0, B_NT = 1 };
enum { EPI_STORE = 0, EPI_SILU = 1, EPI_SIGMOID = 2, EPI_ACCUM = 3, EPI_ATOMIC = 4,
       EPI_STOREB = 5 };  // store bf16 (C cast to u16*)

template<int BLAY, int EPI>
__global__ __launch_bounds__(256) void mfma_gemm(
    const float* __restrict__ A, int lda,
    const float* __restrict__ B, int ldb,
    const float* __restrict__ bias,
    float* __restrict__ C, int ldc,
    int M, int K, int Nn, float scale, int kchunk,
    int zk, long long Ah, long long Bh, long long Ch)
{
    __shared__ __align__(16) u16 As[64][40];
    __shared__ __align__(16) u16 Bs[64][40];
    const int t = threadIdx.x;
    const int bm = blockIdx.y * 64, bn = blockIdx.x * 64;
    const int hz = blockIdx.z / zk, kz = blockIdx.z % zk;
    A += (size_t)hz * Ah; B += (size_t)hz * Bh;
    const int lane = t & 63, w = t >> 6;
    const int r0 = (w >> 1) * 32, c0 = (w & 1) * 32;
    const int fr = lane & 15, fk = (lane >> 4) * 8;
    const int ml = t >> 2, k8 = (t & 3) * 8;
    const int kbeg = kz * kchunk;
    const int kend = (kbeg + kchunk < K) ? kbeg + kchunk : K;
    f32x4 acc[2][2] = {};

    for (int k0 = kbeg; k0 < kend; k0 += 32) {
        {
            U8 u;
            if (((lda & 3) == 0) && (k0 + 32 <= kend)) {
                const float* ap = A + (size_t)(bm + ml) * lda + k0 + k8;
                float4 a0 = *(const float4*)ap;
                float4 a1 = *(const float4*)(ap + 4);
                u.u[0]=f2bf(a0.x); u.u[1]=f2bf(a0.y); u.u[2]=f2bf(a0.z); u.u[3]=f2bf(a0.w);
                u.u[4]=f2bf(a1.x); u.u[5]=f2bf(a1.y); u.u[6]=f2bf(a1.z); u.u[7]=f2bf(a1.w);
            } else {
#pragma unroll
                for (int j = 0; j < 8; ++j) {
                    int kk = k0 + k8 + j;
                    u.u[j] = f2bf(kk < kend ? A[(size_t)(bm + ml) * lda + kk] : 0.f);
                }
            }
            *(short8v*)&As[ml][k8] = u.v;
        }
        {
            U8 u;
            if (BLAY == B_NT) {
                if (((ldb & 3) == 0) && (k0 + 32 <= kend) && (bn + ml < Nn)) {
                    const float* bp = B + (size_t)(bn + ml) * ldb + k0 + k8;
                    float4 b0 = *(const float4*)bp;
                    float4 b1 = *(const float4*)(bp + 4);
                    u.u[0]=f2bf(b0.x); u.u[1]=f2bf(b0.y); u.u[2]=f2bf(b0.z); u.u[3]=f2bf(b0.w);
                    u.u[4]=f2bf(b1.x); u.u[5]=f2bf(b1.y); u.u[6]=f2bf(b1.z); u.u[7]=f2bf(b1.w);
                } else {
#pragma unroll
                    for (int j = 0; j < 8; ++j) {
                        int kk = k0 + k8 + j;
                        u.u[j] = f2bf((kk < kend && bn + ml < Nn)
                                      ? B[(size_t)(bn + ml) * ldb + kk] : 0.f);
                    }
                }
            } else {
                int nc = bn + ml;
#pragma unroll
                for (int j = 0; j < 8; ++j) {
                    int kk = k0 + k8 + j;
                    u.u[j] = f2bf((kk < kend && nc < Nn) ? B[(size_t)kk * ldb + nc] : 0.f);
                }
            }
            *(short8v*)&Bs[ml][k8] = u.v;
        }
        __syncthreads();
        short8v a0 = *(const short8v*)&As[r0 + fr][fk];
        short8v a1 = *(const short8v*)&As[r0 + 16 + fr][fk];
        short8v b0 = *(const short8v*)&Bs[c0 + fr][fk];
        short8v b1 = *(const short8v*)&Bs[c0 + 16 + fr][fk];
        acc[0][0] = mfma16(a0, b0, acc[0][0]);
        acc[0][1] = mfma16(a0, b1, acc[0][1]);
        acc[1][0] = mfma16(a1, b0, acc[1][0]);
        acc[1][1] = mfma16(a1, b1, acc[1][1]);
        __syncthreads();
    }
#pragma unroll
    for (int mi = 0; mi < 2; ++mi)
#pragma unroll
    for (int ni = 0; ni < 2; ++ni)
#pragma unroll
    for (int r = 0; r < 4; ++r) {
        int row = bm + r0 + mi * 16 + ((lane >> 4) << 2) + r;
        int col = bn + c0 + ni * 16 + fr;
        if (col >= Nn) continue;
        float v = acc[mi][ni][r];
        if (EPI == EPI_STOREB) {
            ((u16*)C + (size_t)hz * Ch)[(size_t)row * ldc + col] = f2bf(v * scale);
        } else {
            float* cp = C + (size_t)hz * Ch + (size_t)row * ldc + col;
            if (EPI == EPI_STORE)   *cp = v * scale + (bias ? bias[col] : 0.f);
            if (EPI == EPI_SILU)    *cp = v / (1.f + expf(-v));
            if (EPI == EPI_SIGMOID) *cp = 1.f / (1.f + expf(-v));
            if (EPI == EPI_ACCUM)   *cp += v;
            if (EPI == EPI_ATOMIC)  atomicAdd(cp, v);
        }
    }
}

// --------- transpose: in [R][C] f32 -> out [C][R] bf16 ---------
__global__ __launch_bounds__(256) void transpose_bf16(
    const float* __restrict__ in, u16* __restrict__ outT, int R, int C)
{
    __shared__ float tile[64][65];
    const int br = blockIdx.y * 64, bc = blockIdx.x * 64;
    const int t = threadIdx.x, lc = t & 63, q = t >> 6;
#pragma unroll 4
    for (int r = 0; r < 16; ++r) {
        int row = br + q * 16 + r, col = bc + lc;
        tile[q * 16 + r][lc] = (col < C) ? in[(size_t)row * C + col] : 0.f;
    }
    __syncthreads();
#pragma unroll 4
    for (int r = 0; r < 16; ++r) {
        int orow = bc + q * 16 + r;
        int ocol = br + lc;
        if (orow < C) outT[(size_t)orow * R + ocol] = f2bf(tile[lc][q * 16 + r]);
    }
}

// ============ aggP: bf16 A [M][K] @ bf16 BT [Nn][K] -> atomic C; z = h*zk+kz ============
template<int NB>
__global__ __launch_bounds__(256) void aggP(
    const u16* __restrict__ A, int lda,
    const u16* __restrict__ BT, int ldk,
    float* __restrict__ C, int ldc,
    int K, int Nn, int kchunk,
    int zk, long long Ah, long long Bh, long long Ch)
{
    __shared__ __align__(16) u16 As[64][40];
    __shared__ __align__(16) u16 Bs[NB][64][40];
    const int t = threadIdx.x;
    const int bm = blockIdx.y * 64, bn0 = blockIdx.x * 64 * NB;
    const int hz = blockIdx.z / zk, kz = blockIdx.z % zk;
    A += (size_t)hz * Ah; BT += (size_t)hz * Bh; C += (size_t)hz * Ch;
    const int lane = t & 63, w = t >> 6;
    const int r0 = (w >> 1) * 32, c0 = (w & 1) * 32;
    const int fr = lane & 15, fk = (lane >> 4) * 8;
    const int ml = t >> 2, k8 = (t & 3) * 8;
    const int kbeg = kz * kchunk;
    const int kend = (kbeg + kchunk < K) ? kbeg + kchunk : K;
    f32x4 acc[NB][2][2] = {};

    for (int k0 = kbeg; k0 < kend; k0 += 32) {
        *(short8v*)&As[ml][k8] = *(const short8v*)(A + (size_t)(bm + ml) * lda + k0 + k8);
#pragma unroll
        for (int nb = 0; nb < NB; ++nb) {
            int nc = bn0 + nb * 64 + ml;
            short8v z = {};
            *(short8v*)&Bs[nb][ml][k8] = (nc < Nn)
                ? *(const short8v*)(BT + (size_t)nc * ldk + k0 + k8) : z;
        }
        __syncthreads();
        short8v a0 = *(const short8v*)&As[r0 + fr][fk];
        short8v a1 = *(const short8v*)&As[r0 + 16 + fr][fk];
#pragma unroll
        for (int nb = 0; nb < NB; ++nb) {
            short8v b0 = *(const short8v*)&Bs[nb][c0 + fr][fk];
            short8v b1 = *(const short8v*)&Bs[nb][c0 + 16 + fr][fk];
            acc[nb][0][0] = mfma16(a0, b0, acc[nb][0][0]);
            acc[nb][0][1] = mfma16(a0, b1, acc[nb][0][1]);
            acc[nb][1][0] = mfma16(a1, b0, acc[nb][1][0]);
            acc[nb][1][1] = mfma16(a1, b1, acc[nb][1][1]);
        }
        __syncthreads();
    }
#pragma unroll
    for (int nb = 0; nb < NB; ++nb)
#pragma unroll
    for (int mi = 0; mi < 2; ++mi)
#pragma unroll
    for (int ni = 0; ni < 2; ++ni)
#pragma unroll
    for (int r = 0; r < 4; ++r) {
        int row = bm + r0 + mi * 16 + ((lane >> 4) << 2) + r;
        int col = bn0 + nb * 64 + c0 + ni * 16 + fr;
        if (col >= Nn) continue;
        atomicAdd(C + (size_t)row * ldc + col, acc[nb][mi][ni][r]);
    }
}

// ---------------- u precompute ----------------
__global__ void ucompute_kernel(const float* __restrict__ pos, u16* __restrict__ U) {
    int idx = blockIdx.x * 256 + threadIdx.x;
    int n = idx >> 11, m = idx & (N_ - 1);
    float rx = pos[m * 3 + 0] - pos[n * 3 + 0];
    float ry = pos[m * 3 + 1] - pos[n * 3 + 1];
    float rz = pos[m * 3 + 2] - pos[n * 3 + 2];
    float d2 = rx * rx + ry * ry + rz * rz;
    bool valid = d2 > 1e-12f;
    float rinv = valid ? rsqrtf(d2) : 0.f;
    size_t base = (size_t)n * N_ + m;
    const size_t CS = (size_t)N_ * N_;
    U[base]          = f2bf(rx * rinv);
    U[base + CS]     = f2bf(ry * rinv);
    U[base + 2 * CS] = f2bf(rz * rinv);
}

// ============ fused mix: all channels of one degree, one col-tile per block ============
// DEG=1: 3 channels, grid (8 ks, 32, 2 ct), kchunk 256.
// DEG=2: 5 channels, grid (16 ks, 32, 1),  kchunk 128.
template<int DEG>
__global__ __launch_bounds__(256) void mixf_kernel(
    const u16* __restrict__ amb, const u16* __restrict__ U,
    const u16* __restrict__ BT, float* __restrict__ Macc, int kchunk)
{
    constexpr int NCH = (DEG == 1) ? 3 : 5;
    const int bm = blockIdx.y * 64;
    const int colbase = blockIdx.z * 64;
    const size_t CS = (size_t)N_ * N_;
    __shared__ __align__(16) u16 As[NCH][64][40];
    __shared__ __align__(16) u16 Bs[64][40];
    const int t = threadIdx.x, lane = t & 63, w = t >> 6;
    const int r0 = (w >> 1) * 32, c0 = (w & 1) * 32;
    const int fr = lane & 15, fk = (lane >> 4) * 8;
    const int ml = t >> 2, k8 = (t & 3) * 8;
    const int kbeg = blockIdx.x * kchunk, kend = kbeg + kchunk;
    f32x4 acc[NCH][2][2] = {};

    for (int m0 = kbeg; m0 < kend; m0 += 32) {
        const size_t off = (size_t)(bm + ml) * N_ + m0 + k8;
        U8 am8; am8.v = *(const short8v*)(amb + off);
        U8 xv, yv, zv;
        xv.v = *(const short8v*)(U + off);
        yv.v = *(const short8v*)(U + CS + off);
        zv.v = *(const short8v*)(U + 2 * CS + off);
        if (DEG == 1) {
            U8 o0, o1, o2;
#pragma unroll
            for (int j = 0; j < 8; ++j) {
                float a = bf2f(am8.u[j]);
                o0.u[j] = f2bf(a * bf2f(xv.u[j]));
                o1.u[j] = f2bf(a * bf2f(yv.u[j]));
                o2.u[j] = f2bf(a * bf2f(zv.u[j]));
            }
            *(short8v*)&As[0][ml][k8] = o0.v;
            *(short8v*)&As[1][ml][k8] = o1.v;
            *(short8v*)&As[2][ml][k8] = o2.v;
        } else {
            U8 o[5];
#pragma unroll
            for (int j = 0; j < 8; ++j) {
                float a = bf2f(am8.u[j]);
                float ux = bf2f(xv.u[j]), uy = bf2f(yv.u[j]), uz = bf2f(zv.u[j]);
                o[0].u[j] = f2bf(a * C2_ * ux * uy);
                o[1].u[j] = f2bf(a * C2_ * uy * uz);
                o[2].u[j] = f2bf((ux*ux + uy*uy + uz*uz > 0.5f)
                                 ? a * 0.5f * (3.f * uz * uz - 1.f) : 0.f);
                o[3].u[j] = f2bf(a * C2_ * ux * uz);
                o[4].u[j] = f2bf(a * 0.5f * C2_ * (ux * ux - uy * uy));
            }
#pragma unroll
            for (int c = 0; c < 5; ++c) *(short8v*)&As[c][ml][k8] = o[c].v;
        }
        {
            int nc = colbase + ml;
            short8v z = {};
            *(short8v*)&Bs[ml][k8] = (DEG == 1 || nc < 32)
                ? *(const short8v*)(BT + (size_t)nc * N_ + m0 + k8) : z;
        }
        __syncthreads();
        short8v b0 = *(const short8v*)&Bs[c0 + fr][fk];
        short8v b1 = *(const short8v*)&Bs[c0 + 16 + fr][fk];
#pragma unroll
        for (int c = 0; c < NCH; ++c) {
            short8v a0 = *(const short8v*)&As[c][r0 + fr][fk];
            short8v a1 = *(const short8v*)&As[c][r0 + 16 + fr][fk];
            acc[c][0][0] = mfma16(a0, b0, acc[c][0][0]);
            acc[c][0][1] = mfma16(a0, b1, acc[c][0][1]);
            acc[c][1][0] = mfma16(a1, b0, acc[c][1][0]);
            acc[c][1][1] = mfma16(a1, b1, acc[c][1][1]);
        }
        __syncthreads();
    }
#pragma unroll
    for (int c = 0; c < NCH; ++c)
#pragma unroll
    for (int mi = 0; mi < 2; ++mi)
#pragma unroll
    for (int ni = 0; ni < 2; ++ni)
#pragma unroll
    for (int r = 0; r < 4; ++r) {
        int row = bm + r0 + mi * 16 + ((lane >> 4) << 2) + r;
        int col = colbase + c0 + ni * 16 + fr;
        float v = acc[c][mi][ni][r];
        if (DEG == 1)
            atomicAdd(&Macc[(size_t)c * N_ * 128 + (size_t)row * 128 + col], v);
        else if (col < 32)
            atomicAdd(&Macc[(size_t)3 * N_ * 128 + (size_t)c * N_ * 32
                            + (size_t)row * 32 + col], v);
    }
}

// -------- combine: x12 += Macc --------
__global__ void mix_combine(const float* __restrict__ Macc, float* __restrict__ x12) {
    int idx = blockIdx.x * 256 + threadIdx.x;
    if (idx >= N_ * X12W) return;
    int n = idx / X12W, j = idx % X12W;
    float v;
    if (j < 384) {
        int e = j / 3, c = j - 3 * e;
        v = Macc[(size_t)c * N_ * 128 + (size_t)n * 128 + e];
    } else {
        int jj = j - 384;
        int e = jj / 5, c = jj - 5 * e;
        v = Macc[(size_t)3 * N_ * 128 + (size_t)c * N_ * 32 + (size_t)n * 32 + e];
    }
    x12[idx] += v;
}

// ------- fused 4-head softmax: normalize P_h (bf16, in place) + write am bf16 -------
__global__ void softmax4(u16* __restrict__ Sb, u16* __restrict__ amb) {
    int n = blockIdx.x, t = threadIdx.x;  // 256 threads, 8 elems each
    __shared__ float red[256];
    const size_t NN = (size_t)N_ * N_;
    float amv[8] = {};
    for (int h = 0; h < H_; ++h) {
        u16* Sp = Sb + (size_t)h * NN + (size_t)n * N_ + t * 8;
        U8 sv; sv.v = *(const short8v*)Sp;
        float s[8];
#pragma unroll
        for (int j = 0; j < 8; ++j) s[j] = bf2f(sv.u[j]);
        float mx = s[0];
#pragma unroll
        for (int j = 1; j < 8; ++j) mx = fmaxf(mx, s[j]);
        red[t] = mx; __syncthreads();
        for (int st = 128; st > 0; st >>= 1) { if (t < st) red[t] = fmaxf(red[t], red[t + st]); __syncthreads(); }
        mx = red[0]; __syncthreads();
        float sum = 0.f;
#pragma unroll
        for (int j = 0; j < 8; ++j) { s[j] = expf(s[j] - mx); sum += s[j]; }
        red[t] = sum; __syncthreads();
        for (int st = 128; st > 0; st >>= 1) { if (t < st) red[t] += red[t + st]; __syncthreads(); }
        float rinv = 1.f / red[0]; __syncthreads();
        U8 pv;
#pragma unroll
        for (int j = 0; j < 8; ++j) {
            float p = s[j] * rinv;
            pv.u[j] = f2bf(p);
            amv[j] += 0.25f * p;
        }
        *(short8v*)Sp = pv.v;
    }
    U8 av;
#pragma unroll
    for (int j = 0; j < 8; ++j) av.u[j] = f2bf(amv[j]);
    *(short8v*)(amb + (size_t)n * N_ + t * 8) = av.v;
}

// ---------------- invariants ----------------
__global__ void invar_kernel(const float* __restrict__ x0, const float* __restrict__ x12,
                             float* __restrict__ inv) {
    int n = blockIdx.x, t = threadIdx.x;
    inv[(size_t)n * F_ + t] = x0[(size_t)n * D0_ + t];
    if (t < 128) {
        const float* p = x12 + (size_t)n * X12W + t * 3;
        inv[(size_t)n * F_ + 256 + t] = sqrtf(p[0]*p[0] + p[1]*p[1] + p[2]*p[2]);
    }
    if (t < 32) {
        const float* p = x12 + (size_t)n * X12W + 384 + t * 5;
        inv[(size_t)n * F_ + 384 + t] =
            sqrtf(p[0]*p[0] + p[1]*p[1] + p[2]*p[2] + p[3]*p[3] + p[4]*p[4]);
    }
}

__global__ void v1_kernel(const float* __restrict__ x12, const float* __restrict__ W,
                          float* __restrict__ Vflat) {
    int m = blockIdx.x, t = threadIdx.x;
    __shared__ float sh[384];
    sh[t] = x12[(size_t)m * X12W + t];
    __syncthreads();
    int e = t / 3, c = t % 3;
    float acc = 0.f;
#pragma unroll 4
    for (int d = 0; d < 128; ++d)
        acc = fmaf(sh[d * 3 + c], W[d * 128 + e], acc);
    Vflat[(size_t)m * X12W + t] = acc;
}

__global__ void v2_kernel(const float* __restrict__ x12, const float* __restrict__ W,
                          float* __restrict__ Vflat) {
    int m = blockIdx.x, t = threadIdx.x;
    __shared__ float sh[160];
    if (t < 160) sh[t] = x12[(size_t)m * X12W + 384 + t];
    __syncthreads();
    if (t < 160) {
        int e = t / 5, c = t % 5;
        float acc = 0.f;
#pragma unroll 4
        for (int d = 0; d < 32; ++d)
            acc = fmaf(sh[d * 5 + c], W[d * 32 + e], acc);
        Vflat[(size_t)m * X12W + 384 + t] = acc;
    }
}

__global__ void gate_kernel(const float* __restrict__ g, float* __restrict__ x12) {
    int idx = blockIdx.x * 256 + threadIdx.x;
    if (idx >= N_ * X12W) return;
    int n = idx / X12W, j = idx % X12W;
    float gv = (j < 384) ? g[n * 160 + j / 3] : g[n * 160 + 128 + (j - 384) / 5];
    x12[idx] *= gv;
}

extern "C" void kernel_launch(void* const* d_in, const int* in_sizes, int n_in,
                              void* d_out, int out_size, void* d_ws, size_t ws_size,
                              hipStream_t stream) {
    const float* x    = (const float*)d_in[0];
    const float* pos  = (const float*)d_in[1];
    const float* embW = (const float*)d_in[2];
    const float* embB = (const float*)d_in[3];
    const float* Wq   = (const float*)d_in[4];
    const float* Wk   = (const float*)d_in[5];
    const float* Wv0  = (const float*)d_in[6];
    const float* Wv1  = (const float*)d_in[7];
    const float* Wv2  = (const float*)d_in[8];
    const float* Ws1  = (const float*)d_in[9];
    const float* Ws2  = (const float*)d_in[10];
    const float* Wffa = (const float*)d_in[11];
    const float* Wffb = (const float*)d_in[12];
    const float* Wg   = (const float*)d_in[13];
    const float* outW = (const float*)d_in[14];
    const float* outB = (const float*)d_in[15];
    float* out = (float*)d_out;

    const size_t NN = (size_t)N_ * N_;
    float* p = (float*)d_ws;
    float* x0    = p; p += N_ * D0_;
    float* x12   = p; p += N_ * X12W;
    float* inv   = p; p += N_ * F_;
    float* q     = p; p += N_ * D0_;
    float* k     = p; p += N_ * D0_;
    float* v0    = p; p += N_ * D0_;
    float* Vflat = p; p += N_ * X12W;
    float* s1    = p; p += N_ * D1_;
    float* s2    = p; p += N_ * D2_;
    float* fft   = p; p += N_ * 512;
    float* gm    = p; p += N_ * 160;
    float* Macc  = p; p += 3 * N_ * 128 + 5 * N_ * 32;
    u16* ub   = (u16*)p;
    u16* Sb   = ub; ub += 4 * NN;        // 4 heads' S/P bf16 (32 MB)
    u16* amb  = ub; ub += NN;            // head-mean attention bf16 (8 MB)
    u16* U    = ub; ub += 3 * NN;        // unit vectors (24 MB)
    u16* v0T  = ub; ub += D0_ * N_;
    u16* s1T  = ub; ub += D1_ * N_;
    u16* s2T  = ub; ub += D2_ * N_;
    u16* VflatT = ub; ub += X12W * N_;

    hipMemsetAsync(x12, 0, (size_t)N_ * X12W * sizeof(float), stream);
    ucompute_kernel<<<(N_ * N_) / 256, 256, 0, stream>>>(pos, U);

    mfma_gemm<B_NN, EPI_STORE><<<dim3(4, 32), 256, 0, stream>>>(
        x, 118, embW, 256, embB, x0, 256, N_, 118, 256, 1.f, 118, 1, 0, 0, 0);

    for (int l = 0; l < L_; ++l) {
        const float* Wq_l   = Wq   + (size_t)l * F_ * 256;
        const float* Wk_l   = Wk   + (size_t)l * F_ * 256;
        const float* Wv0_l  = Wv0  + (size_t)l * 256 * 256;
        const float* Wv1_l  = Wv1  + (size_t)l * 128 * 128;
        const float* Wv2_l  = Wv2  + (size_t)l * 32 * 32;
        const float* Ws1_l  = Ws1  + (size_t)l * 256 * 128;
        const float* Ws2_l  = Ws2  + (size_t)l * 256 * 32;
        const float* Wffa_l = Wffa + (size_t)l * 256 * 512;
        const float* Wffb_l = Wffb + (size_t)l * 512 * 256;
        const float* Wg_l   = Wg   + (size_t)l * F_ * 160;

        hipMemsetAsync(Macc, 0, (3 * N_ * 128 + 5 * N_ * 32) * sizeof(float), stream);
        invar_kernel<<<N_, 256, 0, stream>>>(x0, x12, inv);
        mfma_gemm<B_NN, EPI_STORE><<<dim3(4, 32), 256, 0, stream>>>(
            inv, F_, Wq_l, 256, nullptr, q, 256, N_, F_, 256, 1.f, F_, 1, 0, 0, 0);
        mfma_gemm<B_NN, EPI_STORE><<<dim3(4, 32), 256, 0, stream>>>(
            inv, F_, Wk_l, 256, nullptr, k, 256, N_, F_, 256, 1.f, F_, 1, 0, 0, 0);
        mfma_gemm<B_NN, EPI_STORE><<<dim3(4, 32), 256, 0, stream>>>(
            x0, 256, Wv0_l, 256, nullptr, v0, 256, N_, 256, 256, 1.f, 256, 1, 0, 0, 0);
        mfma_gemm<B_NN, EPI_STORE><<<dim3(2, 32), 256, 0, stream>>>(
            x0, 256, Ws1_l, 128, nullptr, s1, 128, N_, 256, 128, 1.f, 256, 1, 0, 0, 0);
        mfma_gemm<B_NN, EPI_STORE><<<dim3(1, 32), 256, 0, stream>>>(
            x0, 256, Ws2_l, 32, nullptr, s2, 32, N_, 256, 32, 1.f, 256, 1, 0, 0, 0);
        v1_kernel<<<N_, 384, 0, stream>>>(x12, Wv1_l, Vflat);
        v2_kernel<<<N_, 192, 0, stream>>>(x12, Wv2_l, Vflat);

        transpose_bf16<<<dim3(4, 32), 256, 0, stream>>>(v0, v0T, N_, 256);
        transpose_bf16<<<dim3(2, 32), 256, 0, stream>>>(s1, s1T, N_, 128);
        transpose_bf16<<<dim3(1, 32), 256, 0, stream>>>(s2, s2T, N_, 32);
        transpose_bf16<<<dim3(9, 32), 256, 0, stream>>>(Vflat, VflatT, N_, X12W);

        // S_h = (q_h @ k_h^T)/8 -> bf16, all 4 heads in one launch (z = head)
        mfma_gemm<B_NT, EPI_STOREB><<<dim3(32, 32, 4), 256, 0, stream>>>(
            q, 256, k, 256, nullptr, (float*)Sb, N_, N_, 64, N_, 0.125f, 64,
            1, 64, 64, (long long)NN);
        // normalize all heads in place + emit am (bf16)
        softmax4<<<N_, 256, 0, stream>>>(Sb, amb);
        // x0[:, h*64:+64] += P_h @ v0_h : all heads, split-K=8 (z = h*8+ks)
        aggP<1><<<dim3(1, 32, 32), 256, 0, stream>>>(
            Sb, N_, v0T, N_, x0, 256, N_, 64, 256,
            8, (long long)NN, (long long)(64 * N_), 64);

        // agg1+agg2: x12 += am @ Vflat  (3 col-tiles/block, split-K=4)
        aggP<3><<<dim3(3, 32, 4), 256, 0, stream>>>(
            amb, N_, VflatT, N_, x12, X12W, N_, X12W, 512,
            4, 0, 0, 0);
        // fused mix (512 blocks each)
        mixf_kernel<1><<<dim3(8, 32, 2), 256, 0, stream>>>(amb, U, s1T, Macc, 256);
        mixf_kernel<2><<<dim3(16, 32, 1), 256, 0, stream>>>(amb, U, s2T, Macc, 128);
        mix_combine<<<(N_ * X12W + 255) / 256, 256, 0, stream>>>(Macc, x12);

        mfma_gemm<B_NN, EPI_SILU><<<dim3(8, 32), 256, 0, stream>>>(
            x0, 256, Wffa_l, 512, nullptr, fft, 512, N_, 256, 512, 1.f, 256, 1, 0, 0, 0);
        mfma_gemm<B_NN, EPI_ACCUM><<<dim3(4, 32), 256, 0, stream>>>(
            fft, 512, Wffb_l, 256, nullptr, x0, 256, N_, 512, 256, 1.f, 512, 1, 0, 0, 0);

        invar_kernel<<<N_, 256, 0, stream>>>(x0, x12, inv);
        mfma_gemm<B_NN, EPI_SIGMOID><<<dim3(3, 32), 256, 0, stream>>>(
            inv, F_, Wg_l, 160, nullptr, gm, 160, N_, F_, 160, 1.f, F_, 1, 0, 0, 0);
        gate_kernel<<<(N_ * X12W + 255) / 256, 256, 0, stream>>>(gm, x12);
    }

    mfma_gemm<B_NN, EPI_STORE><<<dim3(1, 32), 256, 0, stream>>>(
        x0, 256, outW, NC_, outB, out, NC_, N_, 256, NC_, 1.f, 256, 1, 0, 0, 0);
}